// Round 5
// baseline (432.838 us; speedup 1.0000x reference)
//
#include <hip/hip_runtime.h>

using u16 = unsigned short;
using u32 = unsigned int;
using u64 = unsigned long long;

typedef _Float16 half8 __attribute__((ext_vector_type(8)));
typedef float  f32x4 __attribute__((ext_vector_type(4)));
typedef u32    u32x4 __attribute__((ext_vector_type(4)));
typedef u32    u32x2 __attribute__((ext_vector_type(2)));

#define T_STEPS 24
#define NB 4096
#define NF 1024
#define NH 256
#define NCLS 10
#define MROWS (T_STEPS * NB)   // 98304, row = b*24 + t

// split f32 -> hi + 2^-12*lo (lo stored pre-scaled); per-term err ~2^-23|w|
static __device__ __forceinline__ void f16split(float w, u16& hi, u16& lo) {
  _Float16 h = (_Float16)w;
  float hf = (float)h;
  if (__builtin_fabsf(hf) < 6.103515625e-05f) { h = (_Float16)0.0f; hf = 0.0f; }
  float r = __fmul_rn(__fsub_rn(w, hf), 4096.0f);   // exact residual * 2^12
  _Float16 l = (_Float16)r;
  hi = __builtin_bit_cast(u16, h);
  lo = __builtin_bit_cast(u16, l);
}

// ---------------------------------------------------------------------------
// Prep: (a) W1/W2/W3 -> hi/lo f16 planes [n][{0,K}+k];
// (b) B'[cls][t*256+h] = alpha_t * Wo[cls][h] (alpha in f64), f16 2-plane,
//     padded to 16 cls rows with zeros. alpha linearizes the LI readout:
//     v_final = sum_t alpha_t c_t (no reset -> exactly linear).
// ---------------------------------------------------------------------------
__global__ __launch_bounds__(256) void k_prep(const float* __restrict__ W1,
                                              const float* __restrict__ W2,
                                              const float* __restrict__ W3,
                                              const float* __restrict__ Wo,
                                              u16* __restrict__ W1hl,
                                              u16* __restrict__ W2hl,
                                              u16* __restrict__ W3hl,
                                              u16* __restrict__ Bp) {
  int blk = blockIdx.x, tid = threadIdx.x;
  if (blk < 1536) {
    const float* src; u16* dst; int K; int g;
    if (blk < 1024)      { src = W1; dst = W1hl; K = 1024; g = blk * 256 + tid; }
    else if (blk < 1280) { src = W2; dst = W2hl; K = 256;  g = (blk - 1024) * 256 + tid; }
    else                 { src = W3; dst = W3hl; K = 256;  g = (blk - 1280) * 256 + tid; }
    int n = g / K, k = g - n * K;
    u16 hi, lo;
    f16split(src[g], hi, lo);
    u16* d = dst + (size_t)n * 2 * K + k;
    d[0] = hi;
    d[K] = lo;
  } else {
    int g2 = (blk - 1536) * 256 + tid;      // 0..98303 = 16 cls x 6144
    int cls = g2 / 6144;
    int r = g2 - cls * 6144;
    int t = r >> 8, h = r & 255;
    float val = 0.0f;
    if (cls < NCLS) {
      double s = 0.0, p8 = 1.0;
      for (int m = t + 1; m < 24; ++m) {
        double p9 = 1.0;
        for (int q = 0; q < 23 - m; ++q) p9 *= 0.9;
        s += p9 * p8;
        p8 *= 0.8;
      }
      double alpha = 0.1 * s;               // alpha_23 = 0
      val = (float)(alpha * (double)Wo[cls * 256 + h]);
    }
    u16 hi, lo;
    f16split(val, hi, lo);
    Bp[(size_t)cls * 12288 + t * 256 + h] = hi;
    Bp[(size_t)cls * 12288 + 6144 + t * 256 + h] = lo;
  }
}

// ---------------------------------------------------------------------------
// Encoder: per (b,f) neuron, 24-step constant-current LIF, v_th=1.0.
// Bit-exact vs np. bitsE[(b*24+t)*32 + f/32] bit (f%32)  -- (b,t) row order.
// ---------------------------------------------------------------------------
__global__ __launch_bounds__(256) void k_enc(const float* __restrict__ x,
                                             const float* __restrict__ fsp,
                                             u32* __restrict__ bitsE) {
  int g = blockIdx.x * 256 + threadIdx.x;   // g = b*1024 + f
  int b = g >> 10;
  int lane = threadIdx.x & 63;
  float c2 = __fmul_rn(2.0f, fsp[0]);
  float cur = __fmul_rn(c2, x[g]);
  float v = 0.0f;
  int wpair = ((g & 1023) >> 5) & ~1;
  #pragma unroll
  for (int t = 0; t < T_STEPS; ++t) {
    v = __fadd_rn(v, __fmul_rn(0.1f, __fsub_rn(cur, v)));
    bool s = v > 1.0f;
    if (s) v = 0.0f;
    u64 m = __ballot(s);
    if (lane == 0) {
      u32x2 w; w.x = (u32)m; w.y = (u32)(m >> 32);
      *(u32x2*)(bitsE + (size_t)(b * 24 + t) * 32 + wpair) = w;
    }
  }
}

// ---------------------------------------------------------------------------
// Fused bit-A split-f16 GEMM + LIF. Rows in (b,t) order: tile 96m (=4 b x 24 t)
// x 256n, grid MROWS/96. GEMM identical inner loop to R4 (verified): 4 waves x
// 96m x 64n, 16x16x32 f16 MFMA, global_load_lds width-16 XOR-swizzled staging,
// 64-k super-chunks double-buffered. Then per-wave: transpose 16-h slices of
// the f32 currents through a private LDS region (overlaid on dead staging
// buf0), run the 24-step LIF per lane-neuron, ballot -> spike bits (b,t order).
// ---------------------------------------------------------------------------
template <int KDIM>
__global__ __launch_bounds__(256, 2) void k_gemm_lif(const u32* __restrict__ bits,
                                                     const u16* __restrict__ Whl,
                                                     u32* __restrict__ bitsOut,
                                                     const float* __restrict__ esp,
                                                     float sm) {
  constexpr int KTOT  = 2 * KDIM;
  constexpr int NSC   = KTOT / 64;     // super-chunks of 64 k
  constexpr int NCHB  = KDIM / 32;     // bit words per row
  constexpr int NPAIR = NCHB / 2;      // u32x2 per row (pow2)
  __shared__ __align__(16) u16 Bs[2 * 16384];   // 2 x 32KB staging
  const int tid  = threadIdx.x;
  const int wid  = tid >> 6;
  const int lane = tid & 63;
  const int r0   = blockIdx.x * 96;    // 4 b's x 24 t
  const int noff = wid * 64;           // wave n-slice

  const float a = esp ? __fmul_rn(5.0f, esp[0]) : 1.0f;

  // --- staging: wave covers weight rows [wid*64, wid*64+64)
  const int swz16 = ((lane & 7) ^ (lane >> 3)) * 16;
  const char* gstage = (const char*)Whl +
      (size_t)(wid * 64 + (lane >> 3)) * (KTOT * 2) + swz16;
  const int ldsw = wid * 4096;   // u16 units

  auto stage = [&](int s, int b) {
    const char* g = gstage + (size_t)s * 128;
    #pragma unroll
    for (int r = 0; r < 8; ++r)
      __builtin_amdgcn_global_load_lds(
          (const __attribute__((address_space(1))) u32*)(g + (size_t)r * (8 * KTOT * 2)),
          (__attribute__((address_space(3))) u32*)&Bs[b * 16384 + ldsw + r * 512],
          16, 0, 0);
  };

  // --- A bit rows for 6 m-subtiles
  const u32x2* bp[6];
  #pragma unroll
  for (int ms = 0; ms < 6; ++ms)
    bp[ms] = (const u32x2*)(bits + (size_t)(r0 + ms * 16 + (lane & 15)) * NCHB);

  const int bsh = (lane >> 4) * 8;
  auto expand = [&](u32 word, u32 av) -> half8 {
    u32 by = (word >> bsh) & 0xFFu;
    u32 sp = by * 0x8001u;
    u32x4 d;
    d.x = (sp & 0x10001u) * av;
    d.y = ((sp >> 2) & 0x10001u) * av;
    d.z = ((sp >> 4) & 0x10001u) * av;
    d.w = ((sp >> 6) & 0x10001u) * av;
    return __builtin_bit_cast(half8, d);
  };

  const int rbase = (noff + (lane & 15)) * 64;  // u16 units
  int pu8[2];
  #pragma unroll
  for (int h = 0; h < 2; ++h)
    pu8[h] = (((4 * h + (lane >> 4)) ^ (lane & 7)) * 8);

  f32x4 acc[6][4];
  #pragma unroll
  for (int ms = 0; ms < 6; ++ms)
    #pragma unroll
    for (int ns = 0; ns < 4; ++ns)
      #pragma unroll
      for (int i = 0; i < 4; ++i) acc[ms][ns][i] = 0.0f;

  stage(0, 0);
  u32x2 bw[6];
  #pragma unroll
  for (int ms = 0; ms < 6; ++ms) bw[ms] = bp[ms][0];

  #pragma unroll 2
  for (int s = 0; s < NSC; ++s) {
    __syncthreads();   // buf[s&1] staged; all waves done with other buf
    if (s + 1 < NSC) stage(s + 1, (s + 1) & 1);

    u32x2 nb[6];
    if (s + 1 < NSC) {
      const int pi = (s + 1) & (NPAIR - 1);
      #pragma unroll
      for (int ms = 0; ms < 6; ++ms) nb[ms] = bp[ms][pi];
    }

    const u32 av = (s < NSC / 2) ? 0x3C00u : 0x0C00u;   // f16 1.0 / 2^-12
    const int bufo = (s & 1) * 16384;
    #pragma unroll
    for (int h = 0; h < 2; ++h) {
      half8 afr[6];
      #pragma unroll
      for (int ms = 0; ms < 6; ++ms)
        afr[ms] = expand(h ? bw[ms].y : bw[ms].x, av);
      #pragma unroll
      for (int ns = 0; ns < 4; ++ns) {
        half8 bfr = *(const half8*)&Bs[bufo + rbase + ns * 1024 + pu8[h]];
        #pragma unroll
        for (int ms = 0; ms < 6; ++ms)
          acc[ms][ns] = __builtin_amdgcn_mfma_f32_16x16x32_f16(afr[ms], bfr,
                                                               acc[ms][ns], 0, 0, 0);
      }
    }
    if (s + 1 < NSC) {
      #pragma unroll
      for (int ms = 0; ms < 6; ++ms) bw[ms] = nb[ms];
    }
  }

  // --- fused LIF: per-wave private f32 region in dead staging buf0.
  // C/D layout: col = lane&15, row = (lane>>4)*4 + i  (verified R3/R4)
  float* reg = (float*)Bs + wid * 1664;   // 96 rows x 17 (pad) = 1632 floats
  const int col = lane & 15;
  const int q   = lane >> 4;
  u16* bo16 = (u16*)bitsOut;

  #pragma unroll
  for (int ns = 0; ns < 4; ++ns) {
    #pragma unroll
    for (int ms = 0; ms < 6; ++ms) {
      #pragma unroll
      for (int i = 0; i < 4; ++i)
        reg[(ms * 16 + q * 4 + i) * 17 + col] =
            __fmul_rn(sm, __fmul_rn(a, acc[ms][ns][i]));
    }
    __syncthreads();   // lgkm flush: writes visible to all lanes of this wave
    // neuron: b = q (0..3), h' = col (0..15) within h-slice noff + ns*16
    float v = 0.0f, ii = 0.0f;
    #pragma unroll
    for (int t = 0; t < T_STEPS; ++t) {
      float cv = reg[(q * 24 + t) * 17 + col];
      float vdec = __fadd_rn(v, __fmul_rn(0.1f, __fsub_rn(ii, v)));
      float idec = __fmul_rn(0.8f, ii);
      bool z = vdec > 0.33f;
      v = z ? 0.0f : vdec;
      ii = __fadd_rn(idec, cv);
      u64 m = __ballot(z);
      if (col == 0) {
        u16 chunk = (u16)(m >> (16 * q));
        bo16[(size_t)(r0 + q * 24 + t) * 16 + wid * 4 + ns] = chunk;
      }
    }
    __syncthreads();   // all lanes done reading before next ns overwrites
  }
}

// ---------------------------------------------------------------------------
// Final readout: out[4096][10] = z3bits @ B'^T, K' = 2*6144 (hi|lo planes).
// A row b = bits3[b*24*8 .. +192 words) -- contiguous in (b,t) order.
// ---------------------------------------------------------------------------
__global__ __launch_bounds__(256) void k_gfin(const u32* __restrict__ bits3,
                                              const u16* __restrict__ Bp,
                                              float* __restrict__ out) {
  const int tid  = threadIdx.x;
  const int wid  = tid >> 6;
  const int lane = tid & 63;
  const int r0   = (blockIdx.x * 4 + wid) * 16;
  const u32* brow = bits3 + (size_t)(r0 + (lane & 15)) * 192;
  const int bsh = (lane >> 4) * 8;
  const int n = lane & 15;
  const u16* bpn = Bp + (size_t)n * 12288 + (lane >> 4) * 8;
  f32x4 acc;
  #pragma unroll
  for (int i = 0; i < 4; ++i) acc[i] = 0.0f;
  #pragma unroll
  for (int p = 0; p < 2; ++p) {
    const u32 av = p ? 0x0C00u : 0x3C00u;
    #pragma unroll 8
    for (int j = 0; j < 192; ++j) {
      u32 by = (brow[j] >> bsh) & 0xFFu;
      u32 sp = by * 0x8001u;
      u32x4 d;
      d.x = (sp & 0x10001u) * av;
      d.y = ((sp >> 2) & 0x10001u) * av;
      d.z = ((sp >> 4) & 0x10001u) * av;
      d.w = ((sp >> 6) & 0x10001u) * av;
      half8 afr = __builtin_bit_cast(half8, d);
      half8 bfr = *(const half8*)(bpn + p * 6144 + j * 32);
      acc = __builtin_amdgcn_mfma_f32_16x16x32_f16(afr, bfr, acc, 0, 0, 0);
    }
  }
  if (n < NCLS) {
    const int row = r0 + (lane >> 4) * 4;
    #pragma unroll
    for (int i = 0; i < 4; ++i)
      out[(size_t)(row + i) * NCLS + n] = acc[i];
  }
}

// ---------------------------------------------------------------------------
extern "C" void kernel_launch(void* const* d_in, const int* in_sizes, int n_in,
                              void* d_out, int out_size, void* d_ws, size_t ws_size,
                              hipStream_t stream) {
  const float* x  = (const float*)d_in[0];
  const float* W1 = (const float*)d_in[1];
  const float* W2 = (const float*)d_in[2];
  const float* W3 = (const float*)d_in[3];
  const float* Wo = (const float*)d_in[4];
  const float* fs = (const float*)d_in[5];
  const float* es = (const float*)d_in[6];

  char* ws = (char*)d_ws;
  const size_t off_bitsE  = 0;                                    // 12.58 MB
  const size_t off_bitsZ1 = off_bitsE  + (size_t)MROWS * 32 * 4;
  const size_t off_bitsZ2 = off_bitsZ1 + (size_t)MROWS * 8 * 4;   // 3.15 MB each
  const size_t off_w1     = off_bitsZ2 + (size_t)MROWS * 8 * 4;
  const size_t off_w2     = off_w1 + (size_t)NH * 2 * NF * 2;     // 1.0 MB
  const size_t off_w3     = off_w2 + (size_t)NH * 2 * NH * 2;     // 0.25 MB
  const size_t off_bp     = off_w3 + (size_t)NH * 2 * NH * 2;     // 0.25 MB
  const size_t need       = off_bp + (size_t)16 * 12288 * 2;      // 0.375 MB
  if (ws_size < need) return;

  u32* bitsE  = (u32*)(ws + off_bitsE);
  u32* bitsZ1 = (u32*)(ws + off_bitsZ1);
  u32* bitsZ2 = (u32*)(ws + off_bitsZ2);
  u16* W1hl   = (u16*)(ws + off_w1);
  u16* W2hl   = (u16*)(ws + off_w2);
  u16* W3hl   = (u16*)(ws + off_w3);
  u16* Bp     = (u16*)(ws + off_bp);

  k_prep<<<dim3(1920), dim3(256), 0, stream>>>(W1, W2, W3, Wo, W1hl, W2hl, W3hl, Bp);
  k_enc<<<dim3((NB * NF) / 256), dim3(256), 0, stream>>>(x, fs, bitsE);
  // layer 1: GEMM(K=1024) + fused LIF -> z1 bits
  k_gemm_lif<NF><<<dim3(MROWS / 96), dim3(256), 0, stream>>>(bitsE, W1hl, bitsZ1, es, 1.2f);
  // layer 2
  k_gemm_lif<NH><<<dim3(MROWS / 96), dim3(256), 0, stream>>>(bitsZ1, W2hl, bitsZ2, nullptr, 1.2f);
  // layer 3 (z3 bits reuse Z1 region)
  k_gemm_lif<NH><<<dim3(MROWS / 96), dim3(256), 0, stream>>>(bitsZ2, W3hl, bitsZ1, nullptr, 1.2f);
  // linearized LI readout: out = z3 @ (alpha x Wo)^T
  k_gfin<<<dim3(NB / 64), dim3(256), 0, stream>>>(bitsZ1, Bp, (float*)d_out);
}

// Round 6
// 428.422 us; speedup vs baseline: 1.0103x; 1.0103x over previous
//
#include <hip/hip_runtime.h>

using u16 = unsigned short;
using u32 = unsigned int;
using u64 = unsigned long long;

typedef _Float16 half8 __attribute__((ext_vector_type(8)));
typedef float  f32x4 __attribute__((ext_vector_type(4)));
typedef u32    u32x4 __attribute__((ext_vector_type(4)));
typedef u32    u32x2 __attribute__((ext_vector_type(2)));

#define T_STEPS 24
#define NB 4096
#define NF 1024
#define NH 256
#define NCLS 10
#define MROWS (T_STEPS * NB)   // 98304, row = b*24 + t

// split f32 -> hi + 2^-12*lo (lo stored pre-scaled); per-term err ~2^-23|w|
static __device__ __forceinline__ void f16split(float w, u16& hi, u16& lo) {
  _Float16 h = (_Float16)w;
  float hf = (float)h;
  if (__builtin_fabsf(hf) < 6.103515625e-05f) { h = (_Float16)0.0f; hf = 0.0f; }
  float r = __fmul_rn(__fsub_rn(w, hf), 4096.0f);   // exact residual * 2^12
  _Float16 l = (_Float16)r;
  hi = __builtin_bit_cast(u16, h);
  lo = __builtin_bit_cast(u16, l);
}

// ---------------------------------------------------------------------------
// Prep: W1/W2/W3 -> hi/lo f16 planes; B'[cls][t*256+h] = alpha_t*Wo[cls][h]
// (f64 alpha; linearized LI readout), f16 2-plane, padded to 16 cls rows.
// ---------------------------------------------------------------------------
__global__ __launch_bounds__(256) void k_prep(const float* __restrict__ W1,
                                              const float* __restrict__ W2,
                                              const float* __restrict__ W3,
                                              const float* __restrict__ Wo,
                                              u16* __restrict__ W1hl,
                                              u16* __restrict__ W2hl,
                                              u16* __restrict__ W3hl,
                                              u16* __restrict__ Bp) {
  int blk = blockIdx.x, tid = threadIdx.x;
  if (blk < 1536) {
    const float* src; u16* dst; int K; int g;
    if (blk < 1024)      { src = W1; dst = W1hl; K = 1024; g = blk * 256 + tid; }
    else if (blk < 1280) { src = W2; dst = W2hl; K = 256;  g = (blk - 1024) * 256 + tid; }
    else                 { src = W3; dst = W3hl; K = 256;  g = (blk - 1280) * 256 + tid; }
    int n = g / K, k = g - n * K;
    u16 hi, lo;
    f16split(src[g], hi, lo);
    u16* d = dst + (size_t)n * 2 * K + k;
    d[0] = hi;
    d[K] = lo;
  } else {
    int g2 = (blk - 1536) * 256 + tid;      // 0..98303 = 16 cls x 6144
    int cls = g2 / 6144;
    int r = g2 - cls * 6144;
    int t = r >> 8, h = r & 255;
    float val = 0.0f;
    if (cls < NCLS) {
      double s = 0.0, p8 = 1.0;
      for (int m = t + 1; m < 24; ++m) {
        double p9 = 1.0;
        for (int q = 0; q < 23 - m; ++q) p9 *= 0.9;
        s += p9 * p8;
        p8 *= 0.8;
      }
      double alpha = 0.1 * s;
      val = (float)(alpha * (double)Wo[cls * 256 + h]);
    }
    u16 hi, lo;
    f16split(val, hi, lo);
    Bp[(size_t)cls * 12288 + t * 256 + h] = hi;
    Bp[(size_t)cls * 12288 + 6144 + t * 256 + h] = lo;
  }
}

// ---------------------------------------------------------------------------
// Encoder: bit-exact 24-step constant-current LIF, v_th=1.0.
// bitsE[(b*24+t)*32 + f/32] bit (f%32).
// ---------------------------------------------------------------------------
__global__ __launch_bounds__(256) void k_enc(const float* __restrict__ x,
                                             const float* __restrict__ fsp,
                                             u32* __restrict__ bitsE) {
  int g = blockIdx.x * 256 + threadIdx.x;   // g = b*1024 + f
  int b = g >> 10;
  int lane = threadIdx.x & 63;
  float c2 = __fmul_rn(2.0f, fsp[0]);
  float cur = __fmul_rn(c2, x[g]);
  float v = 0.0f;
  int wpair = ((g & 1023) >> 5) & ~1;
  #pragma unroll
  for (int t = 0; t < T_STEPS; ++t) {
    v = __fadd_rn(v, __fmul_rn(0.1f, __fsub_rn(cur, v)));
    bool s = v > 1.0f;
    if (s) v = 0.0f;
    u64 m = __ballot(s);
    if (lane == 0) {
      u32x2 w; w.x = (u32)m; w.y = (u32)(m >> 32);
      *(u32x2*)(bitsE + (size_t)(b * 24 + t) * 32 + wpair) = w;
    }
  }
}

// ---------------------------------------------------------------------------
// Fused bit-A split-f16 GEMM + LIF.  Tile 192m(=8b x 24t) x 128n, grid
// (512 m-tiles, 2 n-tiles).  4 waves x 48m x 128n, acc[3][8].  Staging:
// global_load_lds width-16, XOR-16B-unit swizzle, 16KB buf x2 (dbuf), one
// barrier per 64-k super-chunk.  Epilogue: 2 barriers total; per-wave LDS
// transpose (4 rounds of 32 h-cols), serial 24-step LIF per lane-neuron,
// ballot -> LDS u32 words, final coalesced dwordx4 burst of the block's
// 192x4-word bit tile.
// ---------------------------------------------------------------------------
template <int KDIM>
__global__ __launch_bounds__(256, 3) void k_gemm_lif(const u32* __restrict__ bits,
                                                     const u16* __restrict__ Whl,
                                                     u32* __restrict__ bitsOut,
                                                     const float* __restrict__ esp,
                                                     float sm) {
  constexpr int KTOT  = 2 * KDIM;
  constexpr int NSC   = KTOT / 64;     // super-chunks of 64 k
  constexpr int NCHB  = KDIM / 32;     // bit words per row
  constexpr int NPAIR = NCHB / 2;      // u32x2 per row (pow2)
  __shared__ __align__(16) u16 Bs[2 * 8192];   // 2 x 16KB staging
  const int tid   = threadIdx.x;
  const int wid   = tid >> 6;
  const int lane  = tid & 63;
  const int r0    = blockIdx.x * 192;  // 8 b's x 24 t
  const int ntile = blockIdx.y;        // 0/1: h-cols [ntile*128, +128)

  const float a = esp ? __fmul_rn(5.0f, esp[0]) : 1.0f;

  // --- staging: wave stages 32 of the 128 weight rows per super-chunk
  const char* gstage = (const char*)Whl +
      ((size_t)(ntile * 128 + wid * 32 + (lane >> 3)) * KTOT +
       (size_t)(((lane & 7) ^ (lane >> 3)) * 8)) * 2;
  const int ldsw = (wid * 32) * 64;    // u16 units, wave-uniform

  auto stage = [&](int s, int b) {
    const char* g = gstage + (size_t)s * 128;
    #pragma unroll
    for (int r = 0; r < 4; ++r)
      __builtin_amdgcn_global_load_lds(
          (const __attribute__((address_space(1))) u32*)(g + (size_t)r * (8 * KTOT * 2)),
          (__attribute__((address_space(3))) u32*)&Bs[b * 8192 + ldsw + r * 512],
          16, 0, 0);
  };

  // --- A bit rows for 3 m-subtiles (wave m-base = wid*48)
  const u32x2* bp[3];
  #pragma unroll
  for (int ms = 0; ms < 3; ++ms)
    bp[ms] = (const u32x2*)(bits + (size_t)(r0 + wid * 48 + ms * 16 + (lane & 15)) * NCHB);

  const int bsh = (lane >> 4) * 8;
  auto expand = [&](u32 word, u32 av) -> half8 {
    u32 by = (word >> bsh) & 0xFFu;
    u32 sp = by * 0x8001u;
    u32x4 d;
    d.x = (sp & 0x10001u) * av;
    d.y = ((sp >> 2) & 0x10001u) * av;
    d.z = ((sp >> 4) & 0x10001u) * av;
    d.w = ((sp >> 6) & 0x10001u) * av;
    return __builtin_bit_cast(half8, d);
  };

  const int rbase = (lane & 15) * 64;  // u16 units
  int pu8[2];
  #pragma unroll
  for (int h = 0; h < 2; ++h)
    pu8[h] = (((4 * h + (lane >> 4)) ^ (lane & 7)) * 8);

  f32x4 acc[3][8];
  #pragma unroll
  for (int ms = 0; ms < 3; ++ms)
    #pragma unroll
    for (int ns = 0; ns < 8; ++ns)
      #pragma unroll
      for (int i = 0; i < 4; ++i) acc[ms][ns][i] = 0.0f;

  stage(0, 0);
  u32x2 bw[3];
  #pragma unroll
  for (int ms = 0; ms < 3; ++ms) bw[ms] = bp[ms][0];

  #pragma unroll 2
  for (int s = 0; s < NSC; ++s) {
    __syncthreads();   // buf[s&1] staged; all waves done with other buf
    if (s + 1 < NSC) stage(s + 1, (s + 1) & 1);

    u32x2 nb[3];
    if (s + 1 < NSC) {
      const int pi = (s + 1) & (NPAIR - 1);
      #pragma unroll
      for (int ms = 0; ms < 3; ++ms) nb[ms] = bp[ms][pi];
    }

    const u32 av = (s < NSC / 2) ? 0x3C00u : 0x0C00u;   // f16 1.0 / 2^-12
    const int bufo = (s & 1) * 8192;
    #pragma unroll
    for (int h = 0; h < 2; ++h) {
      half8 afr[3];
      #pragma unroll
      for (int ms = 0; ms < 3; ++ms)
        afr[ms] = expand(h ? bw[ms].y : bw[ms].x, av);
      #pragma unroll
      for (int ns = 0; ns < 8; ++ns) {
        half8 bfr = *(const half8*)&Bs[bufo + rbase + ns * 1024 + pu8[h]];
        #pragma unroll
        for (int ms = 0; ms < 3; ++ms)
          acc[ms][ns] = __builtin_amdgcn_mfma_f32_16x16x32_f16(afr[ms], bfr,
                                                               acc[ms][ns], 0, 0, 0);
      }
    }
    if (s + 1 < NSC) {
      #pragma unroll
      for (int ms = 0; ms < 3; ++ms) bw[ms] = nb[ms];
    }
  }

  // ===== fused LIF epilogue (2 barriers total) =====
  __syncthreads();                       // everyone done reading staging LDS
  // per-wave f32 region: 48 rows x 33 (pad) = 1584 f32; stride 1600 f32/wave
  float* reg = (float*)Bs + wid * 1600;            // bytes [0, 25600)
  u32*  blds = (u32*)((char*)Bs + 26624);          // [192][4] u32 = 3KB

  const int q   = lane >> 4;   // C/D quad (verified: row = q*4+i, col = lane&15)
  const int c16 = lane & 15;
  const int b2  = lane >> 5;   // epilogue neuron: b-pair member
  const int c   = lane & 31;   // h' within 32-col round

  #pragma unroll
  for (int p = 0; p < 4; ++p) {          // h-col rounds of 32 (ns = 2p, 2p+1)
    #pragma unroll
    for (int ms = 0; ms < 3; ++ms)
      #pragma unroll
      for (int j = 0; j < 2; ++j)
        #pragma unroll
        for (int i = 0; i < 4; ++i)
          reg[(ms * 16 + q * 4 + i) * 33 + j * 16 + c16] =
              __fmul_rn(sm, __fmul_rn(a, acc[ms][2 * p + j][i]));
    // per-wave region: in-wave lgkmcnt ordering suffices (no barrier)
    float v = 0.0f, ii = 0.0f;
    #pragma unroll
    for (int t = 0; t < T_STEPS; ++t) {
      float cv = reg[(b2 * 24 + t) * 33 + c];
      float vdec = __fadd_rn(v, __fmul_rn(0.1f, __fsub_rn(ii, v)));
      float idec = __fmul_rn(0.8f, ii);
      bool z = vdec > 0.33f;
      v = z ? 0.0f : vdec;
      ii = __fadd_rn(idec, cv);
      u64 m = __ballot(z);
      if (c == 0)
        blds[((wid * 2 + b2) * 24 + t) * 4 + p] = (u32)(m >> (b2 * 32));
    }
  }
  __syncthreads();
  if (tid < 192) {                        // coalesced 3KB burst
    u32x4 w = *(const u32x4*)&blds[tid * 4];
    *(u32x4*)&bitsOut[(size_t)(r0 + tid) * 8 + ntile * 4] = w;
  }
}

// ---------------------------------------------------------------------------
// Final readout: out[4096][10] = z3bits @ B'^T, K' = 2*6144 (hi|lo planes).
// ---------------------------------------------------------------------------
__global__ __launch_bounds__(256) void k_gfin(const u32* __restrict__ bits3,
                                              const u16* __restrict__ Bp,
                                              float* __restrict__ out) {
  const int tid  = threadIdx.x;
  const int wid  = tid >> 6;
  const int lane = tid & 63;
  const int r0   = (blockIdx.x * 4 + wid) * 16;
  const u32* brow = bits3 + (size_t)(r0 + (lane & 15)) * 192;
  const int bsh = (lane >> 4) * 8;
  const int n = lane & 15;
  const u16* bpn = Bp + (size_t)n * 12288 + (lane >> 4) * 8;
  f32x4 acc;
  #pragma unroll
  for (int i = 0; i < 4; ++i) acc[i] = 0.0f;
  #pragma unroll
  for (int p = 0; p < 2; ++p) {
    const u32 av = p ? 0x0C00u : 0x3C00u;
    #pragma unroll 8
    for (int j = 0; j < 192; ++j) {
      u32 by = (brow[j] >> bsh) & 0xFFu;
      u32 sp = by * 0x8001u;
      u32x4 d;
      d.x = (sp & 0x10001u) * av;
      d.y = ((sp >> 2) & 0x10001u) * av;
      d.z = ((sp >> 4) & 0x10001u) * av;
      d.w = ((sp >> 6) & 0x10001u) * av;
      half8 afr = __builtin_bit_cast(half8, d);
      half8 bfr = *(const half8*)(bpn + p * 6144 + j * 32);
      acc = __builtin_amdgcn_mfma_f32_16x16x32_f16(afr, bfr, acc, 0, 0, 0);
    }
  }
  if (n < NCLS) {
    const int row = r0 + (lane >> 4) * 4;
    #pragma unroll
    for (int i = 0; i < 4; ++i)
      out[(size_t)(row + i) * NCLS + n] = acc[i];
  }
}

// ---------------------------------------------------------------------------
extern "C" void kernel_launch(void* const* d_in, const int* in_sizes, int n_in,
                              void* d_out, int out_size, void* d_ws, size_t ws_size,
                              hipStream_t stream) {
  const float* x  = (const float*)d_in[0];
  const float* W1 = (const float*)d_in[1];
  const float* W2 = (const float*)d_in[2];
  const float* W3 = (const float*)d_in[3];
  const float* Wo = (const float*)d_in[4];
  const float* fs = (const float*)d_in[5];
  const float* es = (const float*)d_in[6];

  char* ws = (char*)d_ws;
  const size_t off_bitsE  = 0;                                    // 12.58 MB
  const size_t off_bitsZ1 = off_bitsE  + (size_t)MROWS * 32 * 4;
  const size_t off_bitsZ2 = off_bitsZ1 + (size_t)MROWS * 8 * 4;   // 3.15 MB each
  const size_t off_w1     = off_bitsZ2 + (size_t)MROWS * 8 * 4;
  const size_t off_w2     = off_w1 + (size_t)NH * 2 * NF * 2;     // 1.0 MB
  const size_t off_w3     = off_w2 + (size_t)NH * 2 * NH * 2;     // 0.25 MB
  const size_t off_bp     = off_w3 + (size_t)NH * 2 * NH * 2;     // 0.25 MB
  const size_t need       = off_bp + (size_t)16 * 12288 * 2;      // 0.375 MB
  if (ws_size < need) return;

  u32* bitsE  = (u32*)(ws + off_bitsE);
  u32* bitsZ1 = (u32*)(ws + off_bitsZ1);
  u32* bitsZ2 = (u32*)(ws + off_bitsZ2);
  u16* W1hl   = (u16*)(ws + off_w1);
  u16* W2hl   = (u16*)(ws + off_w2);
  u16* W3hl   = (u16*)(ws + off_w3);
  u16* Bp     = (u16*)(ws + off_bp);

  k_prep<<<dim3(1920), dim3(256), 0, stream>>>(W1, W2, W3, Wo, W1hl, W2hl, W3hl, Bp);
  k_enc<<<dim3((NB * NF) / 256), dim3(256), 0, stream>>>(x, fs, bitsE);
  // layer 1: GEMM(K=1024) + fused LIF -> z1 bits
  k_gemm_lif<NF><<<dim3(MROWS / 192, 2), dim3(256), 0, stream>>>(bitsE, W1hl, bitsZ1, es, 1.2f);
  // layer 2
  k_gemm_lif<NH><<<dim3(MROWS / 192, 2), dim3(256), 0, stream>>>(bitsZ1, W2hl, bitsZ2, nullptr, 1.2f);
  // layer 3 (z3 bits reuse Z1 region)
  k_gemm_lif<NH><<<dim3(MROWS / 192, 2), dim3(256), 0, stream>>>(bitsZ2, W3hl, bitsZ1, nullptr, 1.2f);
  // linearized LI readout
  k_gfin<<<dim3(NB / 64), dim3(256), 0, stream>>>(bitsZ1, Bp, (float*)d_out);
}

// Round 8
// 389.812 us; speedup vs baseline: 1.1104x; 1.0990x over previous
//
#include <hip/hip_runtime.h>

using u16 = unsigned short;
using u32 = unsigned int;
using u64 = unsigned long long;

typedef _Float16 half8 __attribute__((ext_vector_type(8)));
typedef float  f32x4 __attribute__((ext_vector_type(4)));
typedef u32    u32x4 __attribute__((ext_vector_type(4)));
typedef u32    u32x2 __attribute__((ext_vector_type(2)));

#define T_STEPS 24
#define NB 4096
#define NF 1024
#define NH 256
#define NCLS 10
#define MROWS (T_STEPS * NB)   // 98304, row = b*24 + t

// split f32 -> hi + 2^-12*lo (lo stored pre-scaled); per-term err ~2^-23|w|
static __device__ __forceinline__ void f16split(float w, u16& hi, u16& lo) {
  _Float16 h = (_Float16)w;
  float hf = (float)h;
  if (__builtin_fabsf(hf) < 6.103515625e-05f) { h = (_Float16)0.0f; hf = 0.0f; }
  float r = __fmul_rn(__fsub_rn(w, hf), 4096.0f);   // exact residual * 2^12
  _Float16 l = (_Float16)r;
  hi = __builtin_bit_cast(u16, h);
  lo = __builtin_bit_cast(u16, l);
}

// ---------------------------------------------------------------------------
// Prep: W1/W2/W3 -> hi/lo f16 planes; B'[cls][t*256+h] = alpha_t*Wo[cls][h]
// (f64 alpha; linearized LI readout), f16 2-plane, padded to 16 cls rows.
// ---------------------------------------------------------------------------
__global__ __launch_bounds__(256) void k_prep(const float* __restrict__ W1,
                                              const float* __restrict__ W2,
                                              const float* __restrict__ W3,
                                              const float* __restrict__ Wo,
                                              u16* __restrict__ W1hl,
                                              u16* __restrict__ W2hl,
                                              u16* __restrict__ W3hl,
                                              u16* __restrict__ Bp) {
  int blk = blockIdx.x, tid = threadIdx.x;
  if (blk < 1536) {
    const float* src; u16* dst; int K; int g;
    if (blk < 1024)      { src = W1; dst = W1hl; K = 1024; g = blk * 256 + tid; }
    else if (blk < 1280) { src = W2; dst = W2hl; K = 256;  g = (blk - 1024) * 256 + tid; }
    else                 { src = W3; dst = W3hl; K = 256;  g = (blk - 1280) * 256 + tid; }
    int n = g / K, k = g - n * K;
    u16 hi, lo;
    f16split(src[g], hi, lo);
    u16* d = dst + (size_t)n * 2 * K + k;
    d[0] = hi;
    d[K] = lo;
  } else {
    int g2 = (blk - 1536) * 256 + tid;      // 0..98303 = 16 cls x 6144
    int cls = g2 / 6144;
    int r = g2 - cls * 6144;
    int t = r >> 8, h = r & 255;
    float val = 0.0f;
    if (cls < NCLS) {
      double s = 0.0, p8 = 1.0;
      for (int m = t + 1; m < 24; ++m) {
        double p9 = 1.0;
        for (int qq = 0; qq < 23 - m; ++qq) p9 *= 0.9;
        s += p9 * p8;
        p8 *= 0.8;
      }
      double alpha = 0.1 * s;
      val = (float)(alpha * (double)Wo[cls * 256 + h]);
    }
    u16 hi, lo;
    f16split(val, hi, lo);
    Bp[(size_t)cls * 12288 + t * 256 + h] = hi;
    Bp[(size_t)cls * 12288 + 6144 + t * 256 + h] = lo;
  }
}

// ---------------------------------------------------------------------------
// Encoder: bit-exact 24-step constant-current LIF, v_th=1.0.
// bitsE[(b*24+t)*32 + f/32] bit (f%32).
// ---------------------------------------------------------------------------
__global__ __launch_bounds__(256) void k_enc(const float* __restrict__ x,
                                             const float* __restrict__ fsp,
                                             u32* __restrict__ bitsE) {
  int g = blockIdx.x * 256 + threadIdx.x;   // g = b*1024 + f
  int b = g >> 10;
  int lane = threadIdx.x & 63;
  float c2 = __fmul_rn(2.0f, fsp[0]);
  float cur = __fmul_rn(c2, x[g]);
  float v = 0.0f;
  int wpair = ((g & 1023) >> 5) & ~1;
  #pragma unroll
  for (int t = 0; t < T_STEPS; ++t) {
    v = __fadd_rn(v, __fmul_rn(0.1f, __fsub_rn(cur, v)));
    bool s = v > 1.0f;
    if (s) v = 0.0f;
    u64 m = __ballot(s);
    if (lane == 0) {
      u32x2 w; w.x = (u32)m; w.y = (u32)(m >> 32);
      *(u32x2*)(bitsE + (size_t)(b * 24 + t) * 32 + wpair) = w;
    }
  }
}

// ---------------------------------------------------------------------------
// One Linear+LIF phase of the megakernel, all bounds compile-time (the R7
// runtime-lambda version segfaulted the clang frontend). NSC = K'/64 super-
// chunks; A bit-row stride = NSC words (32 for layer 1 global bits, 8 for
// LDS spike bits). 4 waves as 2m x 2n (48m x 128n each), 16x16x32 f16 MFMA,
// global_load_lds width-16 XOR-swizzled dbuf staging, fused register LIF.
// ---------------------------------------------------------------------------
template <int NSC>
__device__ __forceinline__ void mega_phase(u16* __restrict__ Bs,
                                           const u32* __restrict__ abits,
                                           const u16* __restrict__ wsrc,
                                           u32* __restrict__ zdst,
                                           float scale,
                                           int wid, int lane, int wm, int wn) {
  constexpr int KTOT  = NSC * 64;   // u16 per weight row
  constexpr int NPAIR = NSC / 2;

  const int bsh   = (lane >> 4) * 8;
  const int rbase = (wn * 128 + (lane & 15)) * 64;   // u16 (128 B LDS rows)
  int pu8[2];
  #pragma unroll
  for (int h = 0; h < 2; ++h)
    pu8[h] = (((4 * h + (lane >> 4)) ^ (lane & 7)) * 8);
  const int srow  = wid * 64 + (lane >> 3);          // staged weight row
  const int sunit = ((lane & 7) ^ (lane >> 3)) * 8;  // u16, XOR swizzle
  const int ldsw  = wid * 4096;                      // u16 dest base

  const u16* gs = wsrc + (size_t)srow * KTOT + sunit;

  auto stage = [&](int s, int b) {
    const u16* g = gs + s * 64;
    #pragma unroll
    for (int r = 0; r < 8; ++r)
      __builtin_amdgcn_global_load_lds(
          (const __attribute__((address_space(1))) u32*)(g + (size_t)r * 8 * KTOT),
          (__attribute__((address_space(3))) u32*)&Bs[b * 16384 + ldsw + r * 512],
          16, 0, 0);
  };

  int arow[3];
  #pragma unroll
  for (int ms = 0; ms < 3; ++ms)
    arow[ms] = wm * 48 + ms * 16 + (lane & 15);

  auto expand = [&](u32 word, u32 av) -> half8 {
    u32 by = (word >> bsh) & 0xFFu;
    u32 sp = by * 0x8001u;
    u32x4 d;
    d.x = (sp & 0x10001u) * av;
    d.y = ((sp >> 2) & 0x10001u) * av;
    d.z = ((sp >> 4) & 0x10001u) * av;
    d.w = ((sp >> 6) & 0x10001u) * av;
    return __builtin_bit_cast(half8, d);
  };

  f32x4 acc[3][8];
  #pragma unroll
  for (int ms = 0; ms < 3; ++ms)
    #pragma unroll
    for (int ns = 0; ns < 8; ++ns)
      #pragma unroll
      for (int i = 0; i < 4; ++i) acc[ms][ns][i] = 0.0f;

  stage(0, 0);
  u32x2 bw[3];
  #pragma unroll
  for (int ms = 0; ms < 3; ++ms)
    bw[ms] = *(const u32x2*)(abits + (size_t)arow[ms] * NSC);

  #pragma unroll 2
  for (int s = 0; s < NSC; ++s) {
    __syncthreads();   // buf[s&1] staged; all waves done with other buf
    if (s + 1 < NSC) stage(s + 1, (s + 1) & 1);
    u32x2 nb[3];
    if (s + 1 < NSC) {
      const int pi = (s + 1) & (NPAIR - 1);
      #pragma unroll
      for (int ms = 0; ms < 3; ++ms)
        nb[ms] = *(const u32x2*)(abits + (size_t)arow[ms] * NSC + 2 * pi);
    }

    const u32 av = (s < NSC / 2) ? 0x3C00u : 0x0C00u;   // f16 1.0 / 2^-12
    const int bufo = (s & 1) * 16384;
    #pragma unroll
    for (int h = 0; h < 2; ++h) {
      half8 afr[3];
      #pragma unroll
      for (int ms = 0; ms < 3; ++ms)
        afr[ms] = expand(h ? bw[ms].y : bw[ms].x, av);
      #pragma unroll
      for (int ns = 0; ns < 8; ++ns) {
        half8 bfr = *(const half8*)&Bs[bufo + rbase + ns * 1024 + pu8[h]];
        #pragma unroll
        for (int ms = 0; ms < 3; ++ms)
          acc[ms][ns] = __builtin_amdgcn_mfma_f32_16x16x32_f16(afr[ms], bfr,
                                                               acc[ms][ns], 0, 0, 0);
      }
    }
    if (s + 1 < NSC) {
      #pragma unroll
      for (int ms = 0; ms < 3; ++ms) bw[ms] = nb[ms];
    }
  }
  __syncthreads();   // staging dead -> reg overlay safe

  // ---- fused LIF: 4 rounds of 32 cols; C/D: col=lane&15, row=q*4+i ----
  float* reg = (float*)Bs + wid * 1600;   // 48 x 33-pad f32, bytes [0,25600)
  const int q   = lane >> 4, c16 = lane & 15;
  const int b2  = lane >> 5, c   = lane & 31;

  #pragma unroll
  for (int r = 0; r < 4; ++r) {
    #pragma unroll
    for (int ms = 0; ms < 3; ++ms)
      #pragma unroll
      for (int j = 0; j < 2; ++j)
        #pragma unroll
        for (int i = 0; i < 4; ++i)
          reg[(ms * 16 + q * 4 + i) * 33 + j * 16 + c16] =
              __fmul_rn(scale, acc[ms][2 * r + j][i]);
    // lane <-> (b2 = lane>>5, h-col c = lane&31); batched cv prefetch
    float cv[24];
    #pragma unroll
    for (int t = 0; t < T_STEPS; ++t)
      cv[t] = reg[(b2 * 24 + t) * 33 + c];
    float v = 0.0f, ii = 0.0f;
    u32 zw = 0;
    #pragma unroll
    for (int t = 0; t < T_STEPS; ++t) {
      float vdec = __fadd_rn(v, __fmul_rn(0.1f, __fsub_rn(ii, v)));
      float idec = __fmul_rn(0.8f, ii);
      bool z = vdec > 0.33f;
      v = z ? 0.0f : vdec;
      ii = __fadd_rn(idec, cv[t]);
      zw |= ((u32)z) << t;
    }
    #pragma unroll
    for (int t = 0; t < T_STEPS; ++t) {
      u64 m = __ballot((zw >> t) & 1u);
      if (c == 0)
        zdst[((wm * 2 + b2) * 24 + t) * 8 + wn * 4 + r] = (u32)(m >> (b2 * 32));
    }
  }
  __syncthreads();   // zdst complete; reg reads done before next stage(0)
}

// ---------------------------------------------------------------------------
// MEGAKERNEL: one block = 4 batches (96 rows, (b,t) order) through all three
// Linear+LIF layers; z1/z2 spike bits never leave LDS.
// ---------------------------------------------------------------------------
__global__ __launch_bounds__(256, 2) void k_mega(const u32* __restrict__ bitsE,
                                                 const u16* __restrict__ W1hl,
                                                 const u16* __restrict__ W2hl,
                                                 const u16* __restrict__ W3hl,
                                                 u32* __restrict__ bits3,
                                                 const float* __restrict__ esp) {
  __shared__ __align__(16) u16 Bs[2 * 16384];   // 64 KB staging (+ reg overlay)
  __shared__ u32 zA[96 * 8];                    // 3 KB spike bits
  __shared__ u32 zB[96 * 8];                    // 3 KB

  const int tid  = threadIdx.x;
  const int wid  = tid >> 6;
  const int lane = tid & 63;
  const int wm   = wid & 1;
  const int wn   = wid >> 1;
  const int r0   = blockIdx.x * 96;  // 4 batches x 24 t

  const float s1 = __fmul_rn(1.2f, __fmul_rn(5.0f, esp[0]));
  mega_phase<32>(Bs, bitsE + (size_t)r0 * 32, W1hl, zA, s1, wid, lane, wm, wn);
  mega_phase<8>(Bs, zA, W2hl, zB, 1.2f, wid, lane, wm, wn);
  mega_phase<8>(Bs, zB, W3hl, zA, 1.2f, wid, lane, wm, wn);

  // z3 bits -> global, coalesced 3 KB burst
  if (tid < 192) {
    u32x4 w = *(const u32x4*)&zA[(tid >> 1) * 8 + (tid & 1) * 4];
    *(u32x4*)&bits3[(size_t)(r0 + (tid >> 1)) * 8 + (tid & 1) * 4] = w;
  }
}

// ---------------------------------------------------------------------------
// Final readout: out[4096][10] = z3bits @ B'^T, K' = 2*6144 (hi|lo planes).
// ---------------------------------------------------------------------------
__global__ __launch_bounds__(256) void k_gfin(const u32* __restrict__ bits3,
                                              const u16* __restrict__ Bp,
                                              float* __restrict__ out) {
  const int tid  = threadIdx.x;
  const int wid  = tid >> 6;
  const int lane = tid & 63;
  const int r0   = (blockIdx.x * 4 + wid) * 16;
  const u32* brow = bits3 + (size_t)(r0 + (lane & 15)) * 192;
  const int bsh = (lane >> 4) * 8;
  const int n = lane & 15;
  const u16* bpn = Bp + (size_t)n * 12288 + (lane >> 4) * 8;
  f32x4 acc;
  #pragma unroll
  for (int i = 0; i < 4; ++i) acc[i] = 0.0f;
  #pragma unroll
  for (int p = 0; p < 2; ++p) {
    const u32 av = p ? 0x0C00u : 0x3C00u;
    #pragma unroll 8
    for (int j = 0; j < 192; ++j) {
      u32 by = (brow[j] >> bsh) & 0xFFu;
      u32 sp = by * 0x8001u;
      u32x4 d;
      d.x = (sp & 0x10001u) * av;
      d.y = ((sp >> 2) & 0x10001u) * av;
      d.z = ((sp >> 4) & 0x10001u) * av;
      d.w = ((sp >> 6) & 0x10001u) * av;
      half8 afr = __builtin_bit_cast(half8, d);
      half8 bfr = *(const half8*)(bpn + p * 6144 + j * 32);
      acc = __builtin_amdgcn_mfma_f32_16x16x32_f16(afr, bfr, acc, 0, 0, 0);
    }
  }
  if (n < NCLS) {
    const int row = r0 + (lane >> 4) * 4;
    #pragma unroll
    for (int i = 0; i < 4; ++i)
      out[(size_t)(row + i) * NCLS + n] = acc[i];
  }
}

// ---------------------------------------------------------------------------
extern "C" void kernel_launch(void* const* d_in, const int* in_sizes, int n_in,
                              void* d_out, int out_size, void* d_ws, size_t ws_size,
                              hipStream_t stream) {
  const float* x  = (const float*)d_in[0];
  const float* W1 = (const float*)d_in[1];
  const float* W2 = (const float*)d_in[2];
  const float* W3 = (const float*)d_in[3];
  const float* Wo = (const float*)d_in[4];
  const float* fs = (const float*)d_in[5];
  const float* es = (const float*)d_in[6];

  char* ws = (char*)d_ws;
  const size_t off_bitsE = 0;                                   // 12.58 MB
  const size_t off_bits3 = off_bitsE + (size_t)MROWS * 32 * 4;  // 3.15 MB
  const size_t off_w1    = off_bits3 + (size_t)MROWS * 8 * 4;
  const size_t off_w2    = off_w1 + (size_t)NH * 2 * NF * 2;    // 1.0 MB
  const size_t off_w3    = off_w2 + (size_t)NH * 2 * NH * 2;    // 0.25 MB
  const size_t off_bp    = off_w3 + (size_t)NH * 2 * NH * 2;    // 0.25 MB
  const size_t need      = off_bp + (size_t)16 * 12288 * 2;     // 0.375 MB
  if (ws_size < need) return;

  u32* bitsE = (u32*)(ws + off_bitsE);
  u32* bits3 = (u32*)(ws + off_bits3);
  u16* W1hl  = (u16*)(ws + off_w1);
  u16* W2hl  = (u16*)(ws + off_w2);
  u16* W3hl  = (u16*)(ws + off_w3);
  u16* Bp    = (u16*)(ws + off_bp);

  k_prep<<<dim3(1920), dim3(256), 0, stream>>>(W1, W2, W3, Wo, W1hl, W2hl, W3hl, Bp);
  k_enc<<<dim3((NB * NF) / 256), dim3(256), 0, stream>>>(x, fs, bitsE);
  // all three Linear+LIF layers in one dispatch (4 batches/block)
  k_mega<<<dim3(NB / 4), dim3(256), 0, stream>>>(bitsE, W1hl, W2hl, W3hl, bits3, es);
  // linearized LI readout
  k_gfin<<<dim3(NB / 64), dim3(256), 0, stream>>>(bits3, Bp, (float*)d_out);
}

// Round 9
// 350.034 us; speedup vs baseline: 1.2366x; 1.1136x over previous
//
#include <hip/hip_runtime.h>

using u16 = unsigned short;
using u32 = unsigned int;
using u64 = unsigned long long;

typedef _Float16 half8 __attribute__((ext_vector_type(8)));
typedef float  f32x4 __attribute__((ext_vector_type(4)));
typedef u32    u32x4 __attribute__((ext_vector_type(4)));
typedef u32    u32x2 __attribute__((ext_vector_type(2)));

#define T_STEPS 24
#define NB 4096
#define NF 1024
#define NH 256
#define NCLS 10
#define MROWS (T_STEPS * NB)   // 98304, row = b*24 + t

// split f32 -> hi + 2^-12*lo (lo stored pre-scaled); per-term err ~2^-23|w|
static __device__ __forceinline__ void f16split(float w, u16& hi, u16& lo) {
  _Float16 h = (_Float16)w;
  float hf = (float)h;
  if (__builtin_fabsf(hf) < 6.103515625e-05f) { h = (_Float16)0.0f; hf = 0.0f; }
  float r = __fmul_rn(__fsub_rn(w, hf), 4096.0f);   // exact residual * 2^12
  _Float16 l = (_Float16)r;
  hi = __builtin_bit_cast(u16, h);
  lo = __builtin_bit_cast(u16, l);
}

// ---------------------------------------------------------------------------
// Prep: W1/W2/W3 -> hi/lo f16 planes; B'[cls][t*256+h] = alpha_t*Wo[cls][h]
// (f64 alpha; linearized LI readout), f16 2-plane, padded to 16 cls rows.
// ---------------------------------------------------------------------------
__global__ __launch_bounds__(256) void k_prep(const float* __restrict__ W1,
                                              const float* __restrict__ W2,
                                              const float* __restrict__ W3,
                                              const float* __restrict__ Wo,
                                              u16* __restrict__ W1hl,
                                              u16* __restrict__ W2hl,
                                              u16* __restrict__ W3hl,
                                              u16* __restrict__ Bp) {
  int blk = blockIdx.x, tid = threadIdx.x;
  if (blk < 1536) {
    const float* src; u16* dst; int K; int g;
    if (blk < 1024)      { src = W1; dst = W1hl; K = 1024; g = blk * 256 + tid; }
    else if (blk < 1280) { src = W2; dst = W2hl; K = 256;  g = (blk - 1024) * 256 + tid; }
    else                 { src = W3; dst = W3hl; K = 256;  g = (blk - 1280) * 256 + tid; }
    int n = g / K, k = g - n * K;
    u16 hi, lo;
    f16split(src[g], hi, lo);
    u16* d = dst + (size_t)n * 2 * K + k;
    d[0] = hi;
    d[K] = lo;
  } else {
    int g2 = (blk - 1536) * 256 + tid;      // 0..98303 = 16 cls x 6144
    int cls = g2 / 6144;
    int r = g2 - cls * 6144;
    int t = r >> 8, h = r & 255;
    float val = 0.0f;
    if (cls < NCLS) {
      double s = 0.0, p8 = 1.0;
      for (int m = t + 1; m < 24; ++m) {
        double p9 = 1.0;
        for (int qq = 0; qq < 23 - m; ++qq) p9 *= 0.9;
        s += p9 * p8;
        p8 *= 0.8;
      }
      double alpha = 0.1 * s;
      val = (float)(alpha * (double)Wo[cls * 256 + h]);
    }
    u16 hi, lo;
    f16split(val, hi, lo);
    Bp[(size_t)cls * 12288 + t * 256 + h] = hi;
    Bp[(size_t)cls * 12288 + 6144 + t * 256 + h] = lo;
  }
}

// ---------------------------------------------------------------------------
// One Linear+LIF phase. 8 waves as 2m x 4n (wave tile 48m x 64n, acc[3][4]).
// NSC = K'/64 super-chunks; A bits from LDS (row stride ASTRIDE u32 words).
// global_load_lds width-16 XOR-swizzled dbuf staging (4 loads/wave/SC),
// fused register LIF epilogue (2 rounds of 32 cols), spike bits -> zdst
// (stride 8 words/row).
// ---------------------------------------------------------------------------
template <int NSC, int ASTRIDE>
__device__ __forceinline__ void mega_phase(u16* __restrict__ Bs,
                                           const u32* __restrict__ alds,
                                           const u16* __restrict__ wsrc,
                                           u32* __restrict__ zdst,
                                           float scale,
                                           int wid, int lane, int wm, int wn) {
  constexpr int KTOT  = NSC * 64;   // u16 per weight row
  constexpr int NPAIR = NSC / 2;

  const int bsh   = (lane >> 4) * 8;
  const int rbase = (wn * 64 + (lane & 15)) * 64;   // u16 (128 B LDS rows)
  int pu8[2];
  #pragma unroll
  for (int h = 0; h < 2; ++h)
    pu8[h] = (((4 * h + (lane >> 4)) ^ (lane & 7)) * 8);
  const int sunit = ((lane & 7) ^ (lane >> 3)) * 8;  // u16, XOR swizzle
  const u16* gs = wsrc + (size_t)(wid * 32 + (lane >> 3)) * KTOT + sunit;
  const int ldsw = wid * 2048;                       // u16: 32 rows x 64

  auto stage = [&](int s, int b) {
    const u16* g = gs + s * 64;
    #pragma unroll
    for (int r = 0; r < 4; ++r)
      __builtin_amdgcn_global_load_lds(
          (const __attribute__((address_space(1))) u32*)(g + (size_t)r * 8 * KTOT),
          (__attribute__((address_space(3))) u32*)&Bs[b * 16384 + ldsw + r * 512],
          16, 0, 0);
  };

  int arow[3];
  #pragma unroll
  for (int ms = 0; ms < 3; ++ms)
    arow[ms] = (wm * 48 + ms * 16 + (lane & 15)) * ASTRIDE;

  auto expand = [&](u32 word, u32 av) -> half8 {
    u32 by = (word >> bsh) & 0xFFu;
    u32 sp = by * 0x8001u;
    u32x4 d;
    d.x = (sp & 0x10001u) * av;
    d.y = ((sp >> 2) & 0x10001u) * av;
    d.z = ((sp >> 4) & 0x10001u) * av;
    d.w = ((sp >> 6) & 0x10001u) * av;
    return __builtin_bit_cast(half8, d);
  };

  f32x4 acc[3][4];
  #pragma unroll
  for (int ms = 0; ms < 3; ++ms)
    #pragma unroll
    for (int ns = 0; ns < 4; ++ns)
      #pragma unroll
      for (int i = 0; i < 4; ++i) acc[ms][ns][i] = 0.0f;

  stage(0, 0);

  #pragma unroll 2
  for (int s = 0; s < NSC; ++s) {
    __syncthreads();   // buf[s&1] staged; all waves done with other buf
    if (s + 1 < NSC) stage(s + 1, (s + 1) & 1);

    const int pi = (s & (NPAIR - 1)) * 2;
    u32x2 bw[3];
    #pragma unroll
    for (int ms = 0; ms < 3; ++ms)
      bw[ms] = *(const u32x2*)(alds + arow[ms] + pi);

    const u32 av = (s < NSC / 2) ? 0x3C00u : 0x0C00u;   // f16 1.0 / 2^-12
    const int bufo = (s & 1) * 16384;
    #pragma unroll
    for (int h = 0; h < 2; ++h) {
      half8 afr[3];
      #pragma unroll
      for (int ms = 0; ms < 3; ++ms)
        afr[ms] = expand(h ? bw[ms].y : bw[ms].x, av);
      #pragma unroll
      for (int ns = 0; ns < 4; ++ns) {
        half8 bfr = *(const half8*)&Bs[bufo + rbase + ns * 1024 + pu8[h]];
        #pragma unroll
        for (int ms = 0; ms < 3; ++ms)
          acc[ms][ns] = __builtin_amdgcn_mfma_f32_16x16x32_f16(afr[ms], bfr,
                                                               acc[ms][ns], 0, 0, 0);
      }
    }
  }
  __syncthreads();   // staging dead -> reg overlay safe

  // ---- fused LIF: 2 rounds of 32 cols; C/D: col=lane&15, row=q*4+i ----
  float* reg = (float*)Bs + wid * 1600;   // 48 x 33-pad f32 per wave (51.2 KB)
  const int q   = lane >> 4, c16 = lane & 15;
  const int b2  = lane >> 5, c   = lane & 31;

  #pragma unroll
  for (int r = 0; r < 2; ++r) {
    #pragma unroll
    for (int ms = 0; ms < 3; ++ms)
      #pragma unroll
      for (int j = 0; j < 2; ++j)
        #pragma unroll
        for (int i = 0; i < 4; ++i)
          reg[(ms * 16 + q * 4 + i) * 33 + j * 16 + c16] =
              __fmul_rn(scale, acc[ms][2 * r + j][i]);
    // per-wave region: in-wave lgkm ordering suffices (no barrier)
    float v = 0.0f, ii = 0.0f;
    u32 zw = 0;
    #pragma unroll
    for (int t = 0; t < T_STEPS; ++t) {
      float cv = reg[(b2 * 24 + t) * 33 + c];
      float vdec = __fadd_rn(v, __fmul_rn(0.1f, __fsub_rn(ii, v)));
      float idec = __fmul_rn(0.8f, ii);
      bool z = vdec > 0.33f;
      v = z ? 0.0f : vdec;
      ii = __fadd_rn(idec, cv);
      zw |= ((u32)z) << t;
    }
    #pragma unroll
    for (int t = 0; t < T_STEPS; ++t) {
      u64 m = __ballot((zw >> t) & 1u);
      if (c == 0)
        zdst[((wm * 2 + b2) * 24 + t) * 8 + wn * 2 + r] = (u32)(m >> (b2 * 32));
    }
  }
  __syncthreads();   // zdst complete; reg reads done before next stage(0)
}

// ---------------------------------------------------------------------------
// MEGAKERNEL: one block = 4 batches (96 rows, (b,t) order): encoder + all
// three Linear+LIF layers. Encoder/z1/z2 spike bits never leave LDS.
// ---------------------------------------------------------------------------
__global__ __launch_bounds__(512, 4) void k_mega(const float* __restrict__ x,
                                                 const float* __restrict__ fsp,
                                                 const float* __restrict__ esp,
                                                 const u16* __restrict__ W1hl,
                                                 const u16* __restrict__ W2hl,
                                                 const u16* __restrict__ W3hl,
                                                 u32* __restrict__ bits3) {
  __shared__ __align__(16) u16 Bs[2 * 16384];   // 64 KB staging (+ reg overlay)
  __shared__ u32 zE[96 * 34];                   // 13.1 KB enc bits (stride 34; zB overlay)
  __shared__ u32 zA[96 * 8];                    // 3 KB z1 bits (z3 overlay)

  const int tid  = threadIdx.x;
  const int wid  = tid >> 6;
  const int lane = tid & 63;
  const int wm   = wid & 1;
  const int wn   = wid >> 1;          // 0..3
  const int b0   = blockIdx.x * 4;
  const int r0   = blockIdx.x * 96;   // 4 batches x 24 t

  // ---- encoder: wave covers (bb = wid>>1, f in [fbase, fbase+512)) ----
  {
    const int bb = wid >> 1;
    const int fbase = (wid & 1) * 512;
    const float c2 = __fmul_rn(2.0f, fsp[0]);
    float cur[8], v[8];
    #pragma unroll
    for (int j = 0; j < 8; ++j) {
      cur[j] = __fmul_rn(c2, x[(size_t)(b0 + bb) * 1024 + fbase + j * 64 + lane]);
      v[j] = 0.0f;
    }
    #pragma unroll
    for (int t = 0; t < T_STEPS; ++t) {
      #pragma unroll
      for (int j = 0; j < 8; ++j) {
        v[j] = __fadd_rn(v[j], __fmul_rn(0.1f, __fsub_rn(cur[j], v[j])));
        bool s = v[j] > 1.0f;
        if (s) v[j] = 0.0f;
        u64 m = __ballot(s);
        if (lane == 0) {
          int w0 = (bb * 24 + t) * 34 + (fbase >> 5) + 2 * j;
          zE[w0] = (u32)m;
          zE[w0 + 1] = (u32)(m >> 32);
        }
      }
    }
  }
  __syncthreads();

  const float s1 = __fmul_rn(1.2f, __fmul_rn(5.0f, esp[0]));
  mega_phase<32, 34>(Bs, zE, W1hl, zA, s1, wid, lane, wm, wn);
  mega_phase<8, 8>(Bs, zA, W2hl, zE, 1.2f, wid, lane, wm, wn);   // zB = zE region
  mega_phase<8, 8>(Bs, zE, W3hl, zA, 1.2f, wid, lane, wm, wn);   // z3 -> zA region

  // z3 bits -> global, coalesced 3 KB burst
  if (tid < 192) {
    u32x4 w = *(const u32x4*)&zA[(tid >> 1) * 8 + (tid & 1) * 4];
    *(u32x4*)&bits3[(size_t)(r0 + (tid >> 1)) * 8 + (tid & 1) * 4] = w;
  }
}

// ---------------------------------------------------------------------------
// Final readout: out[4096][10] = z3bits @ B'^T, K' = 2*6144 (hi|lo planes).
// ---------------------------------------------------------------------------
__global__ __launch_bounds__(256) void k_gfin(const u32* __restrict__ bits3,
                                              const u16* __restrict__ Bp,
                                              float* __restrict__ out) {
  const int tid  = threadIdx.x;
  const int wid  = tid >> 6;
  const int lane = tid & 63;
  const int r0   = (blockIdx.x * 4 + wid) * 16;
  const u32* brow = bits3 + (size_t)(r0 + (lane & 15)) * 192;
  const int bsh = (lane >> 4) * 8;
  const int n = lane & 15;
  const u16* bpn = Bp + (size_t)n * 12288 + (lane >> 4) * 8;
  f32x4 acc;
  #pragma unroll
  for (int i = 0; i < 4; ++i) acc[i] = 0.0f;
  #pragma unroll
  for (int p = 0; p < 2; ++p) {
    const u32 av = p ? 0x0C00u : 0x3C00u;
    #pragma unroll 8
    for (int j = 0; j < 192; ++j) {
      u32 by = (brow[j] >> bsh) & 0xFFu;
      u32 sp = by * 0x8001u;
      u32x4 d;
      d.x = (sp & 0x10001u) * av;
      d.y = ((sp >> 2) & 0x10001u) * av;
      d.z = ((sp >> 4) & 0x10001u) * av;
      d.w = ((sp >> 6) & 0x10001u) * av;
      half8 afr = __builtin_bit_cast(half8, d);
      half8 bfr = *(const half8*)(bpn + p * 6144 + j * 32);
      acc = __builtin_amdgcn_mfma_f32_16x16x32_f16(afr, bfr, acc, 0, 0, 0);
    }
  }
  if (n < NCLS) {
    const int row = r0 + (lane >> 4) * 4;
    #pragma unroll
    for (int i = 0; i < 4; ++i)
      out[(size_t)(row + i) * NCLS + n] = acc[i];
  }
}

// ---------------------------------------------------------------------------
extern "C" void kernel_launch(void* const* d_in, const int* in_sizes, int n_in,
                              void* d_out, int out_size, void* d_ws, size_t ws_size,
                              hipStream_t stream) {
  const float* x  = (const float*)d_in[0];
  const float* W1 = (const float*)d_in[1];
  const float* W2 = (const float*)d_in[2];
  const float* W3 = (const float*)d_in[3];
  const float* Wo = (const float*)d_in[4];
  const float* fs = (const float*)d_in[5];
  const float* es = (const float*)d_in[6];

  char* ws = (char*)d_ws;
  const size_t off_bits3 = 0;                                   // 3.15 MB
  const size_t off_w1    = off_bits3 + (size_t)MROWS * 8 * 4;
  const size_t off_w2    = off_w1 + (size_t)NH * 2 * NF * 2;    // 1.0 MB
  const size_t off_w3    = off_w2 + (size_t)NH * 2 * NH * 2;    // 0.25 MB
  const size_t off_bp    = off_w3 + (size_t)NH * 2 * NH * 2;    // 0.25 MB
  const size_t need      = off_bp + (size_t)16 * 12288 * 2;     // 0.375 MB
  if (ws_size < need) return;

  u32* bits3 = (u32*)(ws + off_bits3);
  u16* W1hl  = (u16*)(ws + off_w1);
  u16* W2hl  = (u16*)(ws + off_w2);
  u16* W3hl  = (u16*)(ws + off_w3);
  u16* Bp    = (u16*)(ws + off_bp);

  k_prep<<<dim3(1920), dim3(256), 0, stream>>>(W1, W2, W3, Wo, W1hl, W2hl, W3hl, Bp);
  // encoder + all three Linear+LIF layers in one dispatch (4 batches/block)
  k_mega<<<dim3(NB / 4), dim3(512), 0, stream>>>(x, fs, es, W1hl, W2hl, W3hl, bits3);
  // linearized LI readout
  k_gfin<<<dim3(NB / 64), dim3(256), 0, stream>>>(bits3, Bp, (float*)d_out);
}

// Round 10
// 326.751 us; speedup vs baseline: 1.3247x; 1.0713x over previous
//
#include <hip/hip_runtime.h>

using u16 = unsigned short;
using u32 = unsigned int;
using u64 = unsigned long long;

typedef _Float16 half8 __attribute__((ext_vector_type(8)));
typedef float  f32x4 __attribute__((ext_vector_type(4)));
typedef u32    u32x4 __attribute__((ext_vector_type(4)));
typedef u32    u32x2 __attribute__((ext_vector_type(2)));

#define T_STEPS 24
#define NB 4096
#define NF 1024
#define NH 256
#define NCLS 10
#define MROWS (T_STEPS * NB)   // 98304, row = b*24 + t

// split f32 -> hi + 2^-12*lo (lo stored pre-scaled); per-term err ~2^-23|w|
static __device__ __forceinline__ void f16split(float w, u16& hi, u16& lo) {
  _Float16 h = (_Float16)w;
  float hf = (float)h;
  if (__builtin_fabsf(hf) < 6.103515625e-05f) { h = (_Float16)0.0f; hf = 0.0f; }
  float r = __fmul_rn(__fsub_rn(w, hf), 4096.0f);   // exact residual * 2^12
  _Float16 l = (_Float16)r;
  hi = __builtin_bit_cast(u16, h);
  lo = __builtin_bit_cast(u16, l);
}

// ---------------------------------------------------------------------------
// Prep: W1/W2/W3 -> f16 planes INTERLEAVED per 64-k block: row n holds
// [hi(k 0..63) | lo(k 0..63) | hi(k 64..127) | lo(...)...] so consecutive
// 64-k super-chunks in the GEMM are hi/lo of the SAME spike bits.
// B'[cls][t*256+h] = alpha_t*Wo[cls][h] (f64 alpha), 2-plane f16 (hi|lo
// halves, k_gfin layout unchanged), padded to 16 cls rows.
// ---------------------------------------------------------------------------
__global__ __launch_bounds__(256) void k_prep(const float* __restrict__ W1,
                                              const float* __restrict__ W2,
                                              const float* __restrict__ W3,
                                              const float* __restrict__ Wo,
                                              u16* __restrict__ W1hl,
                                              u16* __restrict__ W2hl,
                                              u16* __restrict__ W3hl,
                                              u16* __restrict__ Bp) {
  int blk = blockIdx.x, tid = threadIdx.x;
  if (blk < 1536) {
    const float* src; u16* dst; int K; int g;
    if (blk < 1024)      { src = W1; dst = W1hl; K = 1024; g = blk * 256 + tid; }
    else if (blk < 1280) { src = W2; dst = W2hl; K = 256;  g = (blk - 1024) * 256 + tid; }
    else                 { src = W3; dst = W3hl; K = 256;  g = (blk - 1280) * 256 + tid; }
    int n = g / K, k = g - n * K;
    u16 hi, lo;
    f16split(src[g], hi, lo);
    int p = k >> 6, j = k & 63;
    u16* d = dst + (size_t)n * 2 * K + p * 128 + j;
    d[0] = hi;
    d[64] = lo;
  } else {
    int g2 = (blk - 1536) * 256 + tid;      // 0..98303 = 16 cls x 6144
    int cls = g2 / 6144;
    int r = g2 - cls * 6144;
    int t = r >> 8, h = r & 255;
    float val = 0.0f;
    if (cls < NCLS) {
      double s = 0.0, p8 = 1.0;
      for (int m = t + 1; m < 24; ++m) {
        double p9 = 1.0;
        for (int qq = 0; qq < 23 - m; ++qq) p9 *= 0.9;
        s += p9 * p8;
        p8 *= 0.8;
      }
      double alpha = 0.1 * s;
      val = (float)(alpha * (double)Wo[cls * 256 + h]);
    }
    u16 hi, lo;
    f16split(val, hi, lo);
    Bp[(size_t)cls * 12288 + t * 256 + h] = hi;
    Bp[(size_t)cls * 12288 + 6144 + t * 256 + h] = lo;
  }
}

// ---------------------------------------------------------------------------
// One Linear+LIF phase. 8 waves as 2m x 4n (wave tile 48m x 64n, acc[3][4]).
// NSC = K'/64 super-chunks; consecutive (even,odd) SCs are hi/lo planes of
// the SAME k-range: even SC loads A bits + expands 6 f16 fragments (av=1.0);
// odd SC derives lo fragments in-register via packed mul by 2^-12 (exact).
// global_load_lds width-16 XOR-swizzled dbuf staging; fused register LIF.
// ---------------------------------------------------------------------------
template <int NSC, int ASTRIDE>
__device__ __forceinline__ void mega_phase(u16* __restrict__ Bs,
                                           const u32* __restrict__ alds,
                                           const u16* __restrict__ wsrc,
                                           u32* __restrict__ zdst,
                                           float scale,
                                           int wid, int lane, int wm, int wn) {
  constexpr int KTOT = NSC * 64;   // u16 per weight row

  const int bsh   = (lane >> 4) * 8;
  const int rbase = (wn * 64 + (lane & 15)) * 64;   // u16 (128 B LDS rows)
  int pu8[2];
  #pragma unroll
  for (int h = 0; h < 2; ++h)
    pu8[h] = (((4 * h + (lane >> 4)) ^ (lane & 7)) * 8);
  const int sunit = ((lane & 7) ^ (lane >> 3)) * 8;  // u16, XOR swizzle
  const u16* gs = wsrc + (size_t)(wid * 32 + (lane >> 3)) * KTOT + sunit;
  const int ldsw = wid * 2048;                       // u16: 32 rows x 64

  auto stage = [&](int s, int b) {
    const u16* g = gs + s * 64;
    #pragma unroll
    for (int r = 0; r < 4; ++r)
      __builtin_amdgcn_global_load_lds(
          (const __attribute__((address_space(1))) u32*)(g + (size_t)r * 8 * KTOT),
          (__attribute__((address_space(3))) u32*)&Bs[b * 16384 + ldsw + r * 512],
          16, 0, 0);
  };

  int arow[3];
  #pragma unroll
  for (int ms = 0; ms < 3; ++ms)
    arow[ms] = (wm * 48 + ms * 16 + (lane & 15)) * ASTRIDE;

  auto expand = [&](u32 word) -> half8 {
    u32 by = (word >> bsh) & 0xFFu;
    u32 sp = by * 0x8001u;
    u32x4 d;
    d.x = (sp & 0x10001u) * 0x3C00u;
    d.y = ((sp >> 2) & 0x10001u) * 0x3C00u;
    d.z = ((sp >> 4) & 0x10001u) * 0x3C00u;
    d.w = ((sp >> 6) & 0x10001u) * 0x3C00u;
    return __builtin_bit_cast(half8, d);
  };

  const _Float16 scl = (_Float16)2.44140625e-4f;   // 2^-12, exact in f16
  const half8 sc8 = {scl, scl, scl, scl, scl, scl, scl, scl};

  f32x4 acc[3][4];
  #pragma unroll
  for (int ms = 0; ms < 3; ++ms)
    #pragma unroll
    for (int ns = 0; ns < 4; ++ns)
      #pragma unroll
      for (int i = 0; i < 4; ++i) acc[ms][ns][i] = 0.0f;

  stage(0, 0);

  half8 afr[3][2];
  #pragma unroll 2
  for (int s = 0; s < NSC; ++s) {
    __syncthreads();   // buf[s&1] staged; all waves done with other buf
    if ((s & 1) == 0) {
      // hi SC: fresh bits (words s, s+1 of the row) -> expand at av=1.0
      u32x2 bw[3];
      #pragma unroll
      for (int ms = 0; ms < 3; ++ms)
        bw[ms] = *(const u32x2*)(alds + arow[ms] + s);
      if (s + 1 < NSC) stage(s + 1, (s + 1) & 1);
      #pragma unroll
      for (int ms = 0; ms < 3; ++ms) {
        afr[ms][0] = expand(bw[ms].x);
        afr[ms][1] = expand(bw[ms].y);
      }
    } else {
      // lo SC: same bits, amplitude 2^-12 -- packed mul, exact
      if (s + 1 < NSC) stage(s + 1, (s + 1) & 1);
      #pragma unroll
      for (int ms = 0; ms < 3; ++ms) {
        afr[ms][0] = afr[ms][0] * sc8;
        afr[ms][1] = afr[ms][1] * sc8;
      }
    }

    const int bufo = (s & 1) * 16384;
    #pragma unroll
    for (int h = 0; h < 2; ++h) {
      #pragma unroll
      for (int ns = 0; ns < 4; ++ns) {
        half8 bfr = *(const half8*)&Bs[bufo + rbase + ns * 1024 + pu8[h]];
        #pragma unroll
        for (int ms = 0; ms < 3; ++ms)
          acc[ms][ns] = __builtin_amdgcn_mfma_f32_16x16x32_f16(afr[ms][h], bfr,
                                                               acc[ms][ns], 0, 0, 0);
      }
    }
  }
  __syncthreads();   // staging dead -> reg overlay safe

  // ---- fused LIF: 2 rounds of 32 cols; C/D: col=lane&15, row=q*4+i ----
  float* reg = (float*)Bs + wid * 1600;   // 48 x 33-pad f32 per wave (51.2 KB)
  const int q   = lane >> 4, c16 = lane & 15;
  const int b2  = lane >> 5, c   = lane & 31;

  #pragma unroll
  for (int r = 0; r < 2; ++r) {
    #pragma unroll
    for (int ms = 0; ms < 3; ++ms)
      #pragma unroll
      for (int j = 0; j < 2; ++j)
        #pragma unroll
        for (int i = 0; i < 4; ++i)
          reg[(ms * 16 + q * 4 + i) * 33 + j * 16 + c16] =
              __fmul_rn(scale, acc[ms][2 * r + j][i]);
    // per-wave region: in-wave lgkm ordering suffices (no barrier)
    float v = 0.0f, ii = 0.0f;
    u32 zw = 0;
    #pragma unroll
    for (int t = 0; t < T_STEPS; ++t) {
      float cv = reg[(b2 * 24 + t) * 33 + c];
      float vdec = __fadd_rn(v, __fmul_rn(0.1f, __fsub_rn(ii, v)));
      float idec = __fmul_rn(0.8f, ii);
      bool z = vdec > 0.33f;
      v = z ? 0.0f : vdec;
      ii = __fadd_rn(idec, cv);
      zw |= ((u32)z) << t;
    }
    #pragma unroll
    for (int t = 0; t < T_STEPS; ++t) {
      u64 m = __ballot((zw >> t) & 1u);
      if (c == 0)
        zdst[((wm * 2 + b2) * 24 + t) * 8 + wn * 2 + r] = (u32)(m >> (b2 * 32));
    }
  }
  __syncthreads();   // zdst complete; reg reads done before next stage(0)
}

// ---------------------------------------------------------------------------
// MEGAKERNEL: one block = 4 batches (96 rows, (b,t) order): encoder + all
// three Linear+LIF layers. Encoder/z1/z2 spike bits never leave LDS.
// ---------------------------------------------------------------------------
__global__ __launch_bounds__(512, 4) void k_mega(const float* __restrict__ x,
                                                 const float* __restrict__ fsp,
                                                 const float* __restrict__ esp,
                                                 const u16* __restrict__ W1hl,
                                                 const u16* __restrict__ W2hl,
                                                 const u16* __restrict__ W3hl,
                                                 u32* __restrict__ bits3) {
  __shared__ __align__(16) u16 Bs[2 * 16384];   // 64 KB staging (+ reg overlay)
  __shared__ u32 zE[96 * 34];                   // 13.1 KB enc bits (stride 34; zB overlay)
  __shared__ u32 zA[96 * 8];                    // 3 KB z1 bits (z3 overlay)

  const int tid  = threadIdx.x;
  const int wid  = tid >> 6;
  const int lane = tid & 63;
  const int wm   = wid & 1;
  const int wn   = wid >> 1;          // 0..3
  const int b0   = blockIdx.x * 4;
  const int r0   = blockIdx.x * 96;   // 4 batches x 24 t

  // ---- encoder: wave covers (bb = wid>>1, f in [fbase, fbase+512)) ----
  {
    const int bb = wid >> 1;
    const int fbase = (wid & 1) * 512;
    const float c2 = __fmul_rn(2.0f, fsp[0]);
    float cur[8], v[8];
    #pragma unroll
    for (int j = 0; j < 8; ++j) {
      cur[j] = __fmul_rn(c2, x[(size_t)(b0 + bb) * 1024 + fbase + j * 64 + lane]);
      v[j] = 0.0f;
    }
    #pragma unroll
    for (int t = 0; t < T_STEPS; ++t) {
      #pragma unroll
      for (int j = 0; j < 8; ++j) {
        v[j] = __fadd_rn(v[j], __fmul_rn(0.1f, __fsub_rn(cur[j], v[j])));
        bool s = v[j] > 1.0f;
        if (s) v[j] = 0.0f;
        u64 m = __ballot(s);
        if (lane == 0) {
          int w0 = (bb * 24 + t) * 34 + (fbase >> 5) + 2 * j;
          zE[w0] = (u32)m;
          zE[w0 + 1] = (u32)(m >> 32);
        }
      }
    }
  }
  __syncthreads();

  const float s1 = __fmul_rn(1.2f, __fmul_rn(5.0f, esp[0]));
  mega_phase<32, 34>(Bs, zE, W1hl, zA, s1, wid, lane, wm, wn);
  mega_phase<8, 8>(Bs, zA, W2hl, zE, 1.2f, wid, lane, wm, wn);   // zB = zE region
  mega_phase<8, 8>(Bs, zE, W3hl, zA, 1.2f, wid, lane, wm, wn);   // z3 -> zA region

  // z3 bits -> global, coalesced 3 KB burst
  if (tid < 192) {
    u32x4 w = *(const u32x4*)&zA[(tid >> 1) * 8 + (tid & 1) * 4];
    *(u32x4*)&bits3[(size_t)(r0 + (tid >> 1)) * 8 + (tid & 1) * 4] = w;
  }
}

// ---------------------------------------------------------------------------
// Final readout: out[4096][10] = z3bits @ B'^T, K' = 2*6144 (hi|lo planes).
// ---------------------------------------------------------------------------
__global__ __launch_bounds__(256) void k_gfin(const u32* __restrict__ bits3,
                                              const u16* __restrict__ Bp,
                                              float* __restrict__ out) {
  const int tid  = threadIdx.x;
  const int wid  = tid >> 6;
  const int lane = tid & 63;
  const int r0   = (blockIdx.x * 4 + wid) * 16;
  const u32* brow = bits3 + (size_t)(r0 + (lane & 15)) * 192;
  const int bsh = (lane >> 4) * 8;
  const int n = lane & 15;
  const u16* bpn = Bp + (size_t)n * 12288 + (lane >> 4) * 8;
  f32x4 acc;
  #pragma unroll
  for (int i = 0; i < 4; ++i) acc[i] = 0.0f;
  #pragma unroll
  for (int p = 0; p < 2; ++p) {
    const u32 av = p ? 0x0C00u : 0x3C00u;
    #pragma unroll 8
    for (int j = 0; j < 192; ++j) {
      u32 by = (brow[j] >> bsh) & 0xFFu;
      u32 sp = by * 0x8001u;
      u32x4 d;
      d.x = (sp & 0x10001u) * av;
      d.y = ((sp >> 2) & 0x10001u) * av;
      d.z = ((sp >> 4) & 0x10001u) * av;
      d.w = ((sp >> 6) & 0x10001u) * av;
      half8 afr = __builtin_bit_cast(half8, d);
      half8 bfr = *(const half8*)(bpn + p * 6144 + j * 32);
      acc = __builtin_amdgcn_mfma_f32_16x16x32_f16(afr, bfr, acc, 0, 0, 0);
    }
  }
  if (n < NCLS) {
    const int row = r0 + (lane >> 4) * 4;
    #pragma unroll
    for (int i = 0; i < 4; ++i)
      out[(size_t)(row + i) * NCLS + n] = acc[i];
  }
}

// ---------------------------------------------------------------------------
extern "C" void kernel_launch(void* const* d_in, const int* in_sizes, int n_in,
                              void* d_out, int out_size, void* d_ws, size_t ws_size,
                              hipStream_t stream) {
  const float* x  = (const float*)d_in[0];
  const float* W1 = (const float*)d_in[1];
  const float* W2 = (const float*)d_in[2];
  const float* W3 = (const float*)d_in[3];
  const float* Wo = (const float*)d_in[4];
  const float* fs = (const float*)d_in[5];
  const float* es = (const float*)d_in[6];

  char* ws = (char*)d_ws;
  const size_t off_bits3 = 0;                                   // 3.15 MB
  const size_t off_w1    = off_bits3 + (size_t)MROWS * 8 * 4;
  const size_t off_w2    = off_w1 + (size_t)NH * 2 * NF * 2;    // 1.0 MB
  const size_t off_w3    = off_w2 + (size_t)NH * 2 * NH * 2;    // 0.25 MB
  const size_t off_bp    = off_w3 + (size_t)NH * 2 * NH * 2;    // 0.25 MB
  const size_t need      = off_bp + (size_t)16 * 12288 * 2;     // 0.375 MB
  if (ws_size < need) return;

  u32* bits3 = (u32*)(ws + off_bits3);
  u16* W1hl  = (u16*)(ws + off_w1);
  u16* W2hl  = (u16*)(ws + off_w2);
  u16* W3hl  = (u16*)(ws + off_w3);
  u16* Bp    = (u16*)(ws + off_bp);

  k_prep<<<dim3(1920), dim3(256), 0, stream>>>(W1, W2, W3, Wo, W1hl, W2hl, W3hl, Bp);
  // encoder + all three Linear+LIF layers in one dispatch (4 batches/block)
  k_mega<<<dim3(NB / 4), dim3(512), 0, stream>>>(x, fs, es, W1hl, W2hl, W3hl, bits3);
  // linearized LI readout
  k_gfin<<<dim3(NB / 64), dim3(256), 0, stream>>>(bits3, Bp, (float*)d_out);
}